// Round 14
// baseline (898.250 us; speedup 1.0000x reference)
//
#include <hip/hip_runtime.h>
#include <hip/hip_bf16.h>
#include <math.h>

#define A_   12
#define H_   6
#define N_   96
#define T_   80
#define G_   640
#define E_   132
#define E2_  144
#define ROWS_ 7680

typedef const __hip_bfloat16* bfp;
typedef __hip_bfloat16 bf16;
typedef __attribute__((ext_vector_type(8))) short short8;
typedef __attribute__((ext_vector_type(4))) short short4v;
typedef __attribute__((ext_vector_type(4))) float f32x4;
typedef _Float16 h2 __attribute__((ext_vector_type(2)));
typedef _Float16 h4v __attribute__((ext_vector_type(4)));
union H4 { h4v v; h2 h[2]; };

// ---- weight arena element offsets (in 2-byte units) ----
#define WB_QKV   0                /* [3][576][192]  */
#define WB_OUT   331776           /* [3][192][192]  */
#define WB_FW1   442368           /* [3][768][192]  */
#define WB_FW2   884736           /* [3][192][768]  */
#define WB_GAT   1327104          /* [3][2304][192] (gwl|gwr) */
#define WB_W1    2654208          /* [16][64] BN-folded */
#define WB_W2    2655232          /* [64][256] BN-folded */
#define WB_W3T   2671616          /* [192][256] BN-folded, transposed */
#define WB_GWE   2720768          /* [3][2304]  (fp16) */
#define WB_GATT  2727680          /* [3][1152]  (fp16) */
#define WB_TOT   2731136
// ---- f32 bias arena element offsets ----
#define BB_QKV   0
#define BB_OUT   1728
#define BB_FW1   2304
#define BB_FW2   4608
#define BB_GAT   5184
#define BB_B1    12096
#define BB_B2    12160
#define BB_B3    12416
#define BB_TOT   12608

__device__ __forceinline__ float b2f(bf16 x){ return __bfloat162float(x); }
__device__ __forceinline__ float ldf(const void* p, size_t i, int f){
    return f ? __bfloat162float(((const bf16*)p)[i]) : ((const float*)p)[i];
}

// dtype probe: even uint16s of f32 storage are random mantissa halves.
__global__ void k_detect(const void* sf, int* flag)
{
    const unsigned short* u = (const unsigned short*)sf;
    int sane = 0;
    for (int i = 0; i < 64; i++){
        unsigned short v = u[2*i];
        int e = (v >> 7) & 0xFF;
        if (e == 0 || (e >= 100 && e <= 140)) sane++;
    }
    *flag = (sane >= 48) ? 1 : 0;
}

// ---- convert+transpose all weights into arena (bf16; gwe/gatt fp16); biases f32 ----
__global__ __launch_bounds__(256) void k_convert(
    const void* qkvw, const void* outw, const void* fw1, const void* fw2,
    const void* gwl, const void* gwr, const void* gwe, const void* gatt,
    const void* W1, const void* b1, const void* g1, const void* be1, const void* m1, const void* v1,
    const void* W2, const void* b2, const void* g2, const void* be2, const void* m2, const void* v2,
    const void* W3, const void* b3, const void* g3, const void* be3, const void* m3, const void* v3,
    const void* qkvb, const void* outb, const void* fb1, const void* fb2,
    const void* gbl, const void* gbr,
    const int* flagp, bf16* WB, float* BB)
{
    const int f = *flagp;
    size_t idx = (size_t)blockIdx.x*256 + threadIdx.x;
    if (idx < WB_TOT){
        float v; int ishalf = 0;
        if (idx < WB_OUT){            size_t i=idx-WB_QKV; int l=i/110592; int r=i%110592; int n=r/192, k=r%192;
            v = ldf(qkvw, (size_t)l*110592 + (size_t)k*576 + n, f);
        } else if (idx < WB_FW1){     size_t i=idx-WB_OUT; int l=i/36864; int r=i%36864; int n=r/192, k=r%192;
            v = ldf(outw, (size_t)l*36864 + (size_t)k*192 + n, f);
        } else if (idx < WB_FW2){     size_t i=idx-WB_FW1; int l=i/147456; int r=i%147456; int n=r/192, k=r%192;
            v = ldf(fw1, (size_t)l*147456 + (size_t)k*768 + n, f);
        } else if (idx < WB_GAT){     size_t i=idx-WB_FW2; int l=i/147456; int r=i%147456; int n=r/768, k=r%768;
            v = ldf(fw2, (size_t)l*147456 + (size_t)k*192 + n, f);
        } else if (idx < WB_W1){      size_t i=idx-WB_GAT; int l=i/442368; int r=i%442368; int n=r/192, k=r%192;
            if (n < 1152) v = ldf(gwl, (size_t)l*221184 + (size_t)k*1152 + n, f);
            else          v = ldf(gwr, (size_t)l*221184 + (size_t)k*1152 + (n-1152), f);
        } else if (idx < WB_W2){      size_t i=idx-WB_W1; int o=i%64;
            float s = ldf(g1,o,f)*rsqrtf(ldf(v1,o,f)+1e-5f);
            v = ldf(W1, i, f) * s;
        } else if (idx < WB_W3T){     size_t i=idx-WB_W2; int o=i%256;
            float s = ldf(g2,o,f)*rsqrtf(ldf(v2,o,f)+1e-5f);
            v = ldf(W2, i, f) * s;
        } else if (idx < WB_GWE){     size_t i=idx-WB_W3T; int n=i/256, k=i%256;
            float s = ldf(g3,n,f)*rsqrtf(ldf(v3,n,f)+1e-5f);
            v = ldf(W3, (size_t)k*192 + n, f) * s;
        } else if (idx < WB_GATT){    size_t i=idx-WB_GWE;
            v = ldf(gwe, i, f); ishalf = 1;
        } else {                      size_t i=idx-WB_GATT;
            v = ldf(gatt, i, f); ishalf = 1;
        }
        if (ishalf) ((_Float16*)WB)[idx] = (_Float16)v;
        else        WB[idx] = __float2bfloat16(v);
    } else if (idx < WB_TOT + BB_TOT){
        size_t j = idx - WB_TOT;
        float v;
        if (j < BB_OUT)        v = ldf(qkvb, j, f);
        else if (j < BB_FW1)   v = ldf(outb, j-BB_OUT, f);
        else if (j < BB_FW2)   v = ldf(fb1, j-BB_FW1, f);
        else if (j < BB_GAT)   v = ldf(fb2, j-BB_FW2, f);
        else if (j < BB_B1){   size_t i=j-BB_GAT; int l=i/2304; int o=i%2304;
            v = (o<1152) ? ldf(gbl, (size_t)l*1152+o, f) : ldf(gbr, (size_t)l*1152+o-1152, f);
        } else if (j < BB_B2){ int o=j-BB_B1;
            float s = ldf(g1,o,f)*rsqrtf(ldf(v1,o,f)+1e-5f);
            v = (ldf(b1,o,f)-ldf(m1,o,f))*s + ldf(be1,o,f);
        } else if (j < BB_B3){ int o=j-BB_B2;
            float s = ldf(g2,o,f)*rsqrtf(ldf(v2,o,f)+1e-5f);
            v = (ldf(b2,o,f)-ldf(m2,o,f))*s + ldf(be2,o,f);
        } else {               int o=j-BB_B3;
            float s = ldf(g3,o,f)*rsqrtf(ldf(v3,o,f)+1e-5f);
            v = (ldf(b3,o,f)-ldf(m3,o,f))*s + ldf(be3,o,f);
        }
        BB[j] = v;
    }
}

// ---- MLP stages 1+2: in16 -> 64 -> 256 (relu, BN folded), 16 rows/block ----
__global__ __launch_bounds__(256) void k_mlp_a(
    const void* sf, const int* ids, const void* emb, const int* flagp,
    const bf16* __restrict__ WB, const float* __restrict__ BB, bf16* h2g)
{
    __shared__ float in16[16][16];
    __shared__ float h1[16][64];
    const int f = *flagp;
    int tid = threadIdx.x;
    int row0 = blockIdx.x * 16;
    {
        int r = tid >> 4, i = tid & 15;
        int row = row0 + r;
        float v;
        if (i < 4) v = ldf(sf, (size_t)row*4 + i, f);
        else {
            int id = ids[row / T_]; if (id < 0) id = 0; if (id > 599) id = 599;
            v = ldf(emb, (size_t)id*12 + (i-4), f);
        }
        in16[r][i] = v;
    }
    __syncthreads();
    {
        int o = tid & 63, rg = tid >> 6;
        float acc[4];
        float bv = BB[BB_B1 + o];
        #pragma unroll
        for (int j=0;j<4;j++) acc[j] = bv;
        for (int i=0;i<16;i++){
            float w = b2f(WB[WB_W1 + i*64 + o]);
            #pragma unroll
            for (int j=0;j<4;j++) acc[j] += in16[rg*4+j][i]*w;
        }
        #pragma unroll
        for (int j=0;j<4;j++) h1[rg*4+j][o] = acc[j] > 0.f ? acc[j] : 0.f;
    }
    __syncthreads();
    {
        int o = tid;
        float acc[16];
        float bv = BB[BB_B2 + o];
        #pragma unroll
        for (int r=0;r<16;r++) acc[r] = bv;
        for (int i=0;i<64;i++){
            float w = b2f(WB[WB_W2 + i*256 + o]);
            #pragma unroll
            for (int r=0;r<16;r++) acc[r] += h1[r][i]*w;
        }
        for (int r=0;r<16;r++){
            float v = acc[r] > 0.f ? acc[r] : 0.f;
            h2g[(size_t)(row0+r)*256 + o] = __float2bfloat16(v);
        }
    }
}

// ---- MFMA GEMM (64x64 tile): C = A @ Wt^T + bias ----
// mode 0: bf16 store | 1: GELU bf16 | 2: outf = res + v | 3: relu -> out0(flag dtype) & xf = relu + PE
__global__ __launch_bounds__(256) void k_mgemm(
    const bf16* __restrict__ A, const bf16* __restrict__ Wt, const float* __restrict__ bias,
    bf16* outh, float* outf, const float* __restrict__ res, void* out0, const int* flagp,
    int K, int N, int mode)
{
    __shared__ short As[64*200];
    __shared__ short Bs[64*200];
    int tid = threadIdx.x;
    int w = tid >> 6, lane = tid & 63, q = lane >> 4, li = lane & 15;
    int m0 = blockIdx.x * 64, n0 = blockIdx.y * 64;
    const int f = flagp ? *flagp : 0;
    f32x4 acc[4];
    #pragma unroll
    for (int nt=0;nt<4;nt++) acc[nt] = (f32x4){0.f,0.f,0.f,0.f};
    int nkc = (K + 191) / 192;
    for (int kc = 0; kc < nkc; kc++){
        int kcw = K - kc*192; if (kcw > 192) kcw = 192;
        int vr = kcw >> 3;
        const bf16* Ab = A  + (size_t)m0*K + kc*192;
        const bf16* Bb = Wt + (size_t)n0*K + kc*192;
        for (int idx = tid; idx < 64*vr; idx += 256){
            int r = idx / vr, kv = idx - r*vr;
            *(short8*)&As[r*200 + kv*8] = *(const short8*)&Ab[(size_t)r*K + kv*8];
        }
        for (int idx = tid; idx < 64*vr; idx += 256){
            int r = idx / vr, kv = idx - r*vr;
            *(short8*)&Bs[r*200 + kv*8] = *(const short8*)&Bb[(size_t)r*K + kv*8];
        }
        __syncthreads();
        int kkn = kcw >> 5;
        for (int kk = 0; kk < kkn; kk++){
            int ko = kk*32 + q*8;
            short8 a = *(short8*)&As[(w*16+li)*200 + ko];
            #pragma unroll
            for (int nt = 0; nt < 4; nt++){
                short8 b = *(short8*)&Bs[(nt*16+li)*200 + ko];
                acc[nt] = __builtin_amdgcn_mfma_f32_16x16x32_bf16(a, b, acc[nt], 0, 0, 0);
            }
        }
        __syncthreads();
    }
    int rb = m0 + w*16 + q*4;
    #pragma unroll
    for (int nt = 0; nt < 4; nt++){
        int col = n0 + nt*16 + li;
        float bv = bias[col];
        #pragma unroll
        for (int p = 0; p < 4; p++){
            int row = rb + p;
            float v = acc[nt][p] + bv;
            size_t idx = (size_t)row*N + col;
            if (mode == 0) outh[idx] = __float2bfloat16(v);
            else if (mode == 1) outh[idx] = __float2bfloat16(0.5f*v*(1.f + erff(v*0.70710678118654752f)));
            else if (mode == 2) outf[idx] = v + res[idx];
            else {
                float r2 = v > 0.f ? v : 0.f;
                if (f) ((bf16*)out0)[idx] = __float2bfloat16(r2);
                else   ((float*)out0)[idx] = r2;
                int t = row % T_;
                int i2 = col & ~1;
                float dv = expf((float)i2 * (-9.210340371976184f/192.f));
                float ang = (float)t * dv;
                outf[idx] = r2 + ((col & 1) ? cosf(ang) : sinf(ang));
            }
        }
    }
}

// ---- MFMA GEMM (128x64 tile, K%96==0): mode 0 bf16 | 1 GELU bf16 | 4 fp16 ----
__global__ __launch_bounds__(256) void k_mgemm128(
    const bf16* __restrict__ A, const bf16* __restrict__ Wt, const float* __restrict__ bias,
    bf16* outh, int K, int N, int mode)
{
    __shared__ short As[128*104];
    __shared__ short Bs[64*104];
    int tid = threadIdx.x;
    int w = tid >> 6, lane = tid & 63, q = lane >> 4, li = lane & 15;
    int m0 = blockIdx.x * 128, n0 = blockIdx.y * 64;
    f32x4 acc[2][4];
    #pragma unroll
    for (int mt=0;mt<2;mt++)
        #pragma unroll
        for (int nt=0;nt<4;nt++) acc[mt][nt] = (f32x4){0.f,0.f,0.f,0.f};
    int nkc = K / 96;
    for (int kc = 0; kc < nkc; kc++){
        const bf16* Ab = A  + (size_t)m0*K + kc*96;
        const bf16* Bb = Wt + (size_t)n0*K + kc*96;
        for (int idx = tid; idx < 128*12; idx += 256){
            int r = idx / 12, kv = idx - r*12;
            *(short8*)&As[r*104 + kv*8] = *(const short8*)&Ab[(size_t)r*K + kv*8];
        }
        for (int idx = tid; idx < 64*12; idx += 256){
            int r = idx / 12, kv = idx - r*12;
            *(short8*)&Bs[r*104 + kv*8] = *(const short8*)&Bb[(size_t)r*K + kv*8];
        }
        __syncthreads();
        #pragma unroll
        for (int kk = 0; kk < 3; kk++){
            int ko = kk*32 + q*8;
            short8 b0 = *(short8*)&Bs[(0*16+li)*104 + ko];
            short8 b1 = *(short8*)&Bs[(1*16+li)*104 + ko];
            short8 b2 = *(short8*)&Bs[(2*16+li)*104 + ko];
            short8 b3 = *(short8*)&Bs[(3*16+li)*104 + ko];
            #pragma unroll
            for (int mt = 0; mt < 2; mt++){
                short8 a = *(short8*)&As[(w*32 + mt*16 + li)*104 + ko];
                acc[mt][0] = __builtin_amdgcn_mfma_f32_16x16x32_bf16(a, b0, acc[mt][0], 0, 0, 0);
                acc[mt][1] = __builtin_amdgcn_mfma_f32_16x16x32_bf16(a, b1, acc[mt][1], 0, 0, 0);
                acc[mt][2] = __builtin_amdgcn_mfma_f32_16x16x32_bf16(a, b2, acc[mt][2], 0, 0, 0);
                acc[mt][3] = __builtin_amdgcn_mfma_f32_16x16x32_bf16(a, b3, acc[mt][3], 0, 0, 0);
            }
        }
        __syncthreads();
    }
    #pragma unroll
    for (int mt = 0; mt < 2; mt++){
        int rb = m0 + w*32 + mt*16 + q*4;
        #pragma unroll
        for (int nt = 0; nt < 4; nt++){
            int col = n0 + nt*16 + li;
            float bv = bias[col];
            #pragma unroll
            for (int p = 0; p < 4; p++){
                float v = acc[mt][nt][p] + bv;
                size_t idx = (size_t)(rb+p)*N + col;
                if (mode == 0) outh[idx] = __float2bfloat16(v);
                else if (mode == 1) outh[idx] = __float2bfloat16(0.5f*v*(1.f + erff(v*0.70710678118654752f)));
                else ((_Float16*)outh)[idx] = (_Float16)v;
            }
        }
    }
}

// ---- LayerNorm (one wave per row), optional permute to node order ----
__global__ __launch_bounds__(256) void k_ln(const float* __restrict__ x, const void* g, const void* b,
                     size_t gOff, const int* flagp, bf16* out, int permute)
{
    const int f = *flagp;
    int tid = threadIdx.x;
    int row = blockIdx.x*4 + (tid>>6);
    int lane = tid & 63;
    const float* xr = x + (size_t)row*192;
    float v0 = xr[lane], v1 = xr[lane+64], v2 = xr[lane+128];
    float s = v0+v1+v2;
    float qq = v0*v0+v1*v1+v2*v2;
    #pragma unroll
    for (int off=32; off; off>>=1){ s += __shfl_xor(s, off); qq += __shfl_xor(qq, off); }
    float mean = s * (1.f/192.f);
    float var  = qq * (1.f/192.f) - mean*mean;
    float rs = rsqrtf(var + 1e-5f);
    int orow = row;
    if (permute){ int n = row/T_, t = row%T_; int bb = n/A_, a = n%A_; orow = (bb*T_+t)*A_ + a; }
    bf16* op = out + (size_t)orow*192;
    op[lane]     = __float2bfloat16((v0-mean)*rs*ldf(g,gOff+lane,f)     + ldf(b,gOff+lane,f));
    op[lane+64]  = __float2bfloat16((v1-mean)*rs*ldf(g,gOff+lane+64,f)  + ldf(b,gOff+lane+64,f));
    op[lane+128] = __float2bfloat16((v2-mean)*rs*ldf(g,gOff+lane+128,f) + ldf(b,gOff+lane+128,f));
}

// ---- causal attention, one wave per (seq, head, 16-query tile); online softmax ----
__global__ __launch_bounds__(64) void k_attn(bfp qkv, bf16* attn_o)
{
    __shared__ float Ks[80][32];
    __shared__ float Vs[80][32];
    int bid = blockIdx.x;
    int qt = bid % 5;
    int nh = bid / 5;
    int n = nh / H_, h = nh % H_;
    int tid = threadIdx.x;
    for (int idx = tid; idx < 640; idx += 64){
        int r = idx >> 3, c4 = (idx & 7) << 2;
        const bf16* rp = qkv + (size_t)(n*T_+r)*576 + h*32 + c4;
        short4v kv = *(const short4v*)(rp + 192);
        short4v vv = *(const short4v*)(rp + 384);
        f32x4 kf, vf;
        #pragma unroll
        for (int e=0;e<4;e++){
            kf[e] = __uint_as_float(((unsigned)(unsigned short)kv[e])<<16);
            vf[e] = __uint_as_float(((unsigned)(unsigned short)vv[e])<<16);
        }
        *(f32x4*)&Ks[r][c4] = kf;
        *(f32x4*)&Vs[r][c4] = vf;
    }
    __syncthreads();
    int qi = tid & 15, p = tid >> 4;
    int q = qt*16 + qi;
    float qv[8];
    const bf16* qp = qkv + (size_t)(n*T_+q)*576 + h*32 + p*8;
    #pragma unroll
    for (int c=0;c<8;c++) qv[c] = b2f(qp[c]);
    float m = -1e30f, l = 0.f;
    float acc[8];
    #pragma unroll
    for (int c=0;c<8;c++) acc[c]=0.f;
    int jmax = qt*16 + 15;
    for (int j = 0; j <= jmax; j++){
        float s = 0.f;
        #pragma unroll
        for (int c=0;c<8;c++) s += qv[c]*Ks[j][p*8+c];
        s += __shfl_xor(s, 16);
        s += __shfl_xor(s, 32);
        s *= 0.17677669529663687f;
        if (j > q) s = -1e30f;
        float mn = fmaxf(m, s);
        float corr = expf(m - mn);
        float e = expf(s - mn);
        l = l*corr + e;
        #pragma unroll
        for (int c=0;c<8;c++) acc[c] = acc[c]*corr + e*Vs[j][p*8+c];
        m = mn;
    }
    float inv = 1.f/l;
    bf16* op = attn_o + (size_t)(n*T_+q)*192 + h*32 + p*8;
    #pragma unroll
    for (int c=0;c<8;c++) op[c] = __float2bfloat16(acc[c]*inv);
}

// ---- self-loop attr = mean of incoming edge attrs; one block per graph ----
__global__ __launch_bounds__(192) void k_loopea(const int* __restrict__ eidx, const void* ea,
                                                const int* flagp, float* lea)
{
    __shared__ float s0[A_], s1[A_];
    __shared__ int cnt[A_];
    const int f = *flagp;
    int g = blockIdx.x;
    int tid = threadIdx.x;
    if (tid < A_){ s0[tid] = 0.f; s1[tid] = 0.f; cnt[tid] = 0; }
    __syncthreads();
    if (tid < E_){
        int d = eidx[E_ + tid];
        float a0 = ldf(ea, (size_t)(g*E_+tid)*2,   f);
        float a1 = ldf(ea, (size_t)(g*E_+tid)*2+1, f);
        atomicAdd(&s0[d], a0);
        atomicAdd(&s1[d], a1);
        atomicAdd(&cnt[d], 1);
    }
    __syncthreads();
    if (tid < A_){
        int c = cnt[tid] < 1 ? 1 : cnt[tid];
        lea[(g*A_+tid)*2]   = s0[tid]/(float)c;
        lea[(g*A_+tid)*2+1] = s1[tid]/(float)c;
    }
}

// ---- GAT edge logits: one wave per dense (g,d,s); 16-lane-per-head reduce.
// Pass A: heads 0-3 (64 lanes); pass B: heads 4-5 (lanes 32-63 duplicate heads 4-5,
// only lanes <32 write). XCD-swizzled. alpha layout: [(g*12+d)*12+s][H].
__global__ __launch_bounds__(256) void k_alpha(const _Float16* __restrict__ xlr,
                        const float* __restrict__ lea, const void* ea,
                        const _Float16* __restrict__ gweh, const _Float16* __restrict__ gatth,
                        const int* flagp, float* alpha)
{
    const int f = *flagp;
    int bid = blockIdx.x;
    int xcd = bid & 7, slot = bid >> 3;
    int g = xcd*80 + slot/36;
    int ds = (slot % 36)*4 + (threadIdx.x>>6);
    int lane = threadIdx.x & 63;
    int d = ds / 12, s = ds % 12;
    float f0, f1;
    if (s == d){
        f0 = lea[(g*A_+s)*2]; f1 = lea[(g*A_+s)*2+1];
    } else {
        int el = s*11 + (d < s ? d : d-1);
        f0 = ldf(ea, (size_t)(g*E_+el)*2,   f);
        f1 = ldf(ea, (size_t)(g*E_+el)*2+1, f);
    }
    h2 f0h = (h2){(_Float16)f0, (_Float16)f0};
    h2 f1h = (h2){(_Float16)f1, (_Float16)f1};
    const h2 c06 = (h2){(_Float16)0.6f, (_Float16)0.6f};
    const h2 c04 = (h2){(_Float16)0.4f, (_Float16)0.4f};
    const _Float16* xls = xlr + (size_t)(g*A_+s)*2304;
    const _Float16* xrd = xlr + (size_t)(g*A_+d)*2304 + 1152;
    int sub = lane & 15;
    float* ap = alpha + ((size_t)(g*A_+d)*12 + s)*H_;
    #pragma unroll
    for (int pass = 0; pass < 2; pass++){
        int h = pass ? (4 + ((lane>>4)&1)) : (lane>>4);
        int base = h*192 + sub*12;
        float p = 0.f;
        #pragma unroll
        for (int j = 0; j < 3; j++){
            int o = base + 4*j;
            H4 xl, xr, g0, g1, ga;
            xl.v = *(const h4v*)(xls + o);
            xr.v = *(const h4v*)(xrd + o);
            g0.v = *(const h4v*)(gweh + o);
            g1.v = *(const h4v*)(gweh + 1152 + o);
            ga.v = *(const h4v*)(gatth + o);
            #pragma unroll
            for (int k = 0; k < 2; k++){
                h2 m = xl.h[k] + xr.h[k];
                m = g0.h[k]*f0h + m;
                m = g1.h[k]*f1h + m;
                unsigned mu = __builtin_bit_cast(unsigned, m) & 0x7fff7fffu;
                h2 am = __builtin_bit_cast(h2, mu);
                h2 q = m*c06 + am*c04;
                p = __builtin_amdgcn_fdot2(ga.h[k], q, p, false);
            }
        }
        #pragma unroll
        for (int off=1; off<16; off<<=1) p += __shfl_xor(p, off);
        if (pass == 0){
            if (sub == 0) ap[lane>>4] = p;
        } else {
            if (sub == 0 && lane < 32) ap[4 + (lane>>4)] = p;
        }
    }
}

// ---- GAT segment softmax + aggregate; XCD-swizzled; optional final-output store ----
__global__ __launch_bounds__(192) void k_segagg(const _Float16* __restrict__ xlr,
                         const float* __restrict__ alpha,
                         const void* gbias, size_t gbOff, const int* flagp, float* xf,
                         void* out)
{
    __shared__ float al[12][6];
    __shared__ float w[12][6];
    const int f = *flagp;
    int bid = blockIdx.x;
    int xcd = bid & 7, slot = bid >> 3;
    int gl = xcd*80 + slot/12;
    int a = slot % 12;
    int node = gl*A_ + a;
    int tid = threadIdx.x;
    if (tid < 72) ((float*)al)[tid] = alpha[(size_t)node*72 + tid];
    __syncthreads();
    if (tid < 6){
        float m = -1e30f;
        #pragma unroll
        for (int s=0;s<12;s++) m = fmaxf(m, al[s][tid]);
        float den = 0.f;
        #pragma unroll
        for (int s=0;s<12;s++){ float ex = expf(al[s][tid]-m); w[s][tid] = ex; den += ex; }
        float inv = 1.f/den;
        #pragma unroll
        for (int s=0;s<12;s++) w[s][tid] *= inv;
    }
    __syncthreads();
    int c = tid;
    float acc = 0.f;
    for (int s=0;s<12;s++){
        const _Float16* xp = xlr + (size_t)(gl*A_ + s)*2304 + c;
        #pragma unroll
        for (int h=0;h<6;h++) acc += w[s][h]*(float)xp[h*192];
    }
    int b = gl / T_, t = gl % T_;
    int xrow = (b*A_ + a)*T_ + t;
    size_t idx = (size_t)xrow*192 + c;
    float newv = xf[idx] + acc*(1.f/6.f) + ldf(gbias, gbOff + c, f);
    xf[idx] = newv;
    if (out){
        if (f) ((bf16*)out)[1474560 + idx] = __float2bfloat16(newv);
        else   ((float*)out)[1474560 + idx] = newv;
    }
}

extern "C" void kernel_launch(void* const* d_in, const int* in_sizes, int n_in,
                              void* d_out, int out_size, void* d_ws, size_t ws_size,
                              hipStream_t stream)
{
    const void* sf   = d_in[0];
    const int* ids  = (const int*)d_in[2];
    const int* eidx = (const int*)d_in[3];
    const void* ea   = d_in[4];
    const void* emb  = d_in[5];
    const void *laW1=d_in[6],  *lab1=d_in[7];
    const void *bn1g=d_in[8],  *bn1b=d_in[9],  *bn1m=d_in[10], *bn1v=d_in[11];
    const void *laW2=d_in[12], *lab2=d_in[13];
    const void *bn2g=d_in[14], *bn2b=d_in[15], *bn2m=d_in[16], *bn2v=d_in[17];
    const void *laW3=d_in[18], *lab3=d_in[19];
    const void *bn3g=d_in[20], *bn3b=d_in[21], *bn3m=d_in[22], *bn3v=d_in[23];
    const void *ln1g=d_in[24], *ln1b=d_in[25];
    const void *qkvw=d_in[26], *qkvb=d_in[27];
    const void *outw=d_in[28], *outb=d_in[29];
    const void *ln2g=d_in[30], *ln2b=d_in[31];
    const void *fw1 =d_in[32], *fb1 =d_in[33];
    const void *fw2 =d_in[34], *fb2 =d_in[35];
    const void *gwl =d_in[36], *gbl =d_in[37];
    const void *gwr =d_in[38], *gbr =d_in[39];
    const void *gwe =d_in[40];
    const void *gatt=d_in[41];
    const void *gbias=d_in[42];
    const void *ng  =d_in[43], *nb  =d_in[44];

    float* ws = (float*)d_ws;
    float* xf  = ws;                          // [0, 1474560)
    bf16*  xn  = (bf16*)(ws + 1474560);       // 1,474,560 bf16
    bf16*  qkv = (bf16*)(ws + 2211840);       // 4,423,680 bf16
    bf16*  ao  = (bf16*)(ws + 4423680);       // 1,474,560 bf16
    bf16*  hb  = (bf16*)(ws + 2211840);       // overlays qkv+ao (FFN hidden)
    bf16*  h2g = (bf16*)(ws + 2211840);       // overlays (MLP hidden)
    bf16*  xlr = (bf16*)(ws + 2211840);       // overlays (GAT full lr: 17,694,720 fp16)
    float* lea = ws + 11059200;               // 15,360
    int*  flag = (int*)(ws + 11074560);
    bf16*  WB  = (bf16*)(ws + 11074568);      // 2,731,136 x 2B
    float* BB  = ws + 12440136;               // 12,608 f32
    float* alp = ws + 12452744;               // 552,960 f32 (dense [node][src][head])
    (void)ws_size; (void)in_sizes; (void)n_in; (void)out_size;

    k_detect<<<1, 1, 0, stream>>>(sf, flag);
    k_convert<<<(WB_TOT+BB_TOT+255)/256, 256, 0, stream>>>(
        qkvw, outw, fw1, fw2, gwl, gwr, gwe, gatt,
        laW1, lab1, bn1g, bn1b, bn1m, bn1v,
        laW2, lab2, bn2g, bn2b, bn2m, bn2v,
        laW3, lab3, bn3g, bn3b, bn3m, bn3v,
        qkvb, outb, fb1, fb2, gbl, gbr, flag, WB, BB);
    k_mlp_a<<<ROWS_/16, 256, 0, stream>>>(sf, ids, emb, flag, WB, BB, h2g);
    k_mgemm<<<dim3(ROWS_/64, 3), 256, 0, stream>>>(h2g, WB + WB_W3T, BB + BB_B3,
        nullptr, xf, nullptr, d_out, flag, 256, 192, 3);
    k_loopea<<<G_, 192, 0, stream>>>(eidx, ea, flag, lea);

    for (int l=0; l<3; l++){
        k_ln<<<ROWS_/4, 256, 0, stream>>>(xf, ln1g, ln1b, (size_t)l*192, flag, xn, 0);
        k_mgemm128<<<dim3(ROWS_/128, 9), 256, 0, stream>>>(xn, WB + WB_QKV + (size_t)l*110592,
            BB + BB_QKV + l*576, qkv, 192, 576, 0);
        k_attn<<<N_*H_*5, 64, 0, stream>>>(qkv, ao);
        k_mgemm<<<dim3(ROWS_/64, 3), 256, 0, stream>>>(ao, WB + WB_OUT + (size_t)l*36864,
            BB + BB_OUT + l*192, nullptr, xf, xf, nullptr, nullptr, 192, 192, 2);
        k_ln<<<ROWS_/4, 256, 0, stream>>>(xf, ln2g, ln2b, (size_t)l*192, flag, xn, 0);
        k_mgemm128<<<dim3(ROWS_/128, 12), 256, 0, stream>>>(xn, WB + WB_FW1 + (size_t)l*147456,
            BB + BB_FW1 + l*768, hb, 192, 768, 1);
        k_mgemm<<<dim3(ROWS_/64, 3), 256, 0, stream>>>(hb, WB + WB_FW2 + (size_t)l*147456,
            BB + BB_FW2 + l*192, nullptr, xf, xf, nullptr, nullptr, 768, 192, 2);
        k_ln<<<ROWS_/4, 256, 0, stream>>>(xf, ng, nb, (size_t)l*192, flag, xn, 1);
        k_mgemm128<<<dim3(ROWS_/128, 36), 256, 0, stream>>>(xn, WB + WB_GAT + (size_t)l*442368,
            BB + BB_GAT + l*2304, xlr, 192, 2304, 4);
        k_alpha<<<G_*144/4, 256, 0, stream>>>((const _Float16*)xlr, lea, ea,
            (const _Float16*)(WB + WB_GWE) + (size_t)l*2304,
            (const _Float16*)(WB + WB_GATT) + (size_t)l*1152, flag, alp);
        k_segagg<<<G_*A_, 192, 0, stream>>>((const _Float16*)xlr, alp, gbias, (size_t)l*192, flag, xf,
            l == 2 ? d_out : nullptr);
    }
}

// Round 15
// 809.862 us; speedup vs baseline: 1.1091x; 1.1091x over previous
//
#include <hip/hip_runtime.h>
#include <hip/hip_bf16.h>
#include <math.h>

#define A_   12
#define H_   6
#define N_   96
#define T_   80
#define G_   640
#define E_   132
#define E2_  144
#define ROWS_ 7680

typedef const __hip_bfloat16* bfp;
typedef __hip_bfloat16 bf16;
typedef __attribute__((ext_vector_type(8))) short short8;
typedef __attribute__((ext_vector_type(4))) short short4v;
typedef __attribute__((ext_vector_type(4))) float f32x4;
typedef _Float16 h2 __attribute__((ext_vector_type(2)));

// ---- weight arena element offsets (in 2-byte units) ----
#define WB_QKV   0                /* [3][576][192]  */
#define WB_OUT   331776           /* [3][192][192]  */
#define WB_FW1   442368           /* [3][768][192]  */
#define WB_FW2   884736           /* [3][192][768]  */
#define WB_GAT   1327104          /* [3][2304][192] (gwl|gwr) */
#define WB_W1    2654208          /* [16][64] BN-folded */
#define WB_W2    2655232          /* [64][256] BN-folded */
#define WB_W3T   2671616          /* [192][256] BN-folded, transposed */
#define WB_GWE   2720768          /* [3][2304]  (fp16) */
#define WB_GATT  2727680          /* [3][1152]  (fp16) */
#define WB_TOT   2731136
// ---- f32 bias arena element offsets ----
#define BB_QKV   0
#define BB_OUT   1728
#define BB_FW1   2304
#define BB_FW2   4608
#define BB_GAT   5184
#define BB_B1    12096
#define BB_B2    12160
#define BB_B3    12416
#define BB_TOT   12608

__device__ __forceinline__ float b2f(bf16 x){ return __bfloat162float(x); }
__device__ __forceinline__ float ldf(const void* p, size_t i, int f){
    return f ? __bfloat162float(((const bf16*)p)[i]) : ((const float*)p)[i];
}

// dtype probe: even uint16s of f32 storage are random mantissa halves.
__global__ void k_detect(const void* sf, int* flag)
{
    const unsigned short* u = (const unsigned short*)sf;
    int sane = 0;
    for (int i = 0; i < 64; i++){
        unsigned short v = u[2*i];
        int e = (v >> 7) & 0xFF;
        if (e == 0 || (e >= 100 && e <= 140)) sane++;
    }
    *flag = (sane >= 48) ? 1 : 0;
}

// ---- convert+transpose all weights into arena (bf16; gwe/gatt fp16); biases f32 ----
__global__ __launch_bounds__(256) void k_convert(
    const void* qkvw, const void* outw, const void* fw1, const void* fw2,
    const void* gwl, const void* gwr, const void* gwe, const void* gatt,
    const void* W1, const void* b1, const void* g1, const void* be1, const void* m1, const void* v1,
    const void* W2, const void* b2, const void* g2, const void* be2, const void* m2, const void* v2,
    const void* W3, const void* b3, const void* g3, const void* be3, const void* m3, const void* v3,
    const void* qkvb, const void* outb, const void* fb1, const void* fb2,
    const void* gbl, const void* gbr,
    const int* flagp, bf16* WB, float* BB)
{
    const int f = *flagp;
    size_t idx = (size_t)blockIdx.x*256 + threadIdx.x;
    if (idx < WB_TOT){
        float v; int ishalf = 0;
        if (idx < WB_OUT){            size_t i=idx-WB_QKV; int l=i/110592; int r=i%110592; int n=r/192, k=r%192;
            v = ldf(qkvw, (size_t)l*110592 + (size_t)k*576 + n, f);
        } else if (idx < WB_FW1){     size_t i=idx-WB_OUT; int l=i/36864; int r=i%36864; int n=r/192, k=r%192;
            v = ldf(outw, (size_t)l*36864 + (size_t)k*192 + n, f);
        } else if (idx < WB_FW2){     size_t i=idx-WB_FW1; int l=i/147456; int r=i%147456; int n=r/192, k=r%192;
            v = ldf(fw1, (size_t)l*147456 + (size_t)k*768 + n, f);
        } else if (idx < WB_GAT){     size_t i=idx-WB_FW2; int l=i/147456; int r=i%147456; int n=r/768, k=r%768;
            v = ldf(fw2, (size_t)l*147456 + (size_t)k*192 + n, f);
        } else if (idx < WB_W1){      size_t i=idx-WB_GAT; int l=i/442368; int r=i%442368; int n=r/192, k=r%192;
            if (n < 1152) v = ldf(gwl, (size_t)l*221184 + (size_t)k*1152 + n, f);
            else          v = ldf(gwr, (size_t)l*221184 + (size_t)k*1152 + (n-1152), f);
        } else if (idx < WB_W2){      size_t i=idx-WB_W1; int o=i%64;
            float s = ldf(g1,o,f)*rsqrtf(ldf(v1,o,f)+1e-5f);
            v = ldf(W1, i, f) * s;
        } else if (idx < WB_W3T){     size_t i=idx-WB_W2; int o=i%256;
            float s = ldf(g2,o,f)*rsqrtf(ldf(v2,o,f)+1e-5f);
            v = ldf(W2, i, f) * s;
        } else if (idx < WB_GWE){     size_t i=idx-WB_W3T; int n=i/256, k=i%256;
            float s = ldf(g3,n,f)*rsqrtf(ldf(v3,n,f)+1e-5f);
            v = ldf(W3, (size_t)k*192 + n, f) * s;
        } else if (idx < WB_GATT){    size_t i=idx-WB_GWE;
            v = ldf(gwe, i, f); ishalf = 1;
        } else {                      size_t i=idx-WB_GATT;
            v = ldf(gatt, i, f); ishalf = 1;
        }
        if (ishalf) ((_Float16*)WB)[idx] = (_Float16)v;
        else        WB[idx] = __float2bfloat16(v);
    } else if (idx < WB_TOT + BB_TOT){
        size_t j = idx - WB_TOT;
        float v;
        if (j < BB_OUT)        v = ldf(qkvb, j, f);
        else if (j < BB_FW1)   v = ldf(outb, j-BB_OUT, f);
        else if (j < BB_FW2)   v = ldf(fb1, j-BB_FW1, f);
        else if (j < BB_GAT)   v = ldf(fb2, j-BB_FW2, f);
        else if (j < BB_B1){   size_t i=j-BB_GAT; int l=i/2304; int o=i%2304;
            v = (o<1152) ? ldf(gbl, (size_t)l*1152+o, f) : ldf(gbr, (size_t)l*1152+o-1152, f);
        } else if (j < BB_B2){ int o=j-BB_B1;
            float s = ldf(g1,o,f)*rsqrtf(ldf(v1,o,f)+1e-5f);
            v = (ldf(b1,o,f)-ldf(m1,o,f))*s + ldf(be1,o,f);
        } else if (j < BB_B3){ int o=j-BB_B2;
            float s = ldf(g2,o,f)*rsqrtf(ldf(v2,o,f)+1e-5f);
            v = (ldf(b2,o,f)-ldf(m2,o,f))*s + ldf(be2,o,f);
        } else {               int o=j-BB_B3;
            float s = ldf(g3,o,f)*rsqrtf(ldf(v3,o,f)+1e-5f);
            v = (ldf(b3,o,f)-ldf(m3,o,f))*s + ldf(be3,o,f);
        }
        BB[j] = v;
    }
}

// ---- MLP stages 1+2: in16 -> 64 -> 256 (relu, BN folded), 16 rows/block ----
__global__ __launch_bounds__(256) void k_mlp_a(
    const void* sf, const int* ids, const void* emb, const int* flagp,
    const bf16* __restrict__ WB, const float* __restrict__ BB, bf16* h2g)
{
    __shared__ float in16[16][16];
    __shared__ float h1[16][64];
    const int f = *flagp;
    int tid = threadIdx.x;
    int row0 = blockIdx.x * 16;
    {
        int r = tid >> 4, i = tid & 15;
        int row = row0 + r;
        float v;
        if (i < 4) v = ldf(sf, (size_t)row*4 + i, f);
        else {
            int id = ids[row / T_]; if (id < 0) id = 0; if (id > 599) id = 599;
            v = ldf(emb, (size_t)id*12 + (i-4), f);
        }
        in16[r][i] = v;
    }
    __syncthreads();
    {
        int o = tid & 63, rg = tid >> 6;
        float acc[4];
        float bv = BB[BB_B1 + o];
        #pragma unroll
        for (int j=0;j<4;j++) acc[j] = bv;
        for (int i=0;i<16;i++){
            float w = b2f(WB[WB_W1 + i*64 + o]);
            #pragma unroll
            for (int j=0;j<4;j++) acc[j] += in16[rg*4+j][i]*w;
        }
        #pragma unroll
        for (int j=0;j<4;j++) h1[rg*4+j][o] = acc[j] > 0.f ? acc[j] : 0.f;
    }
    __syncthreads();
    {
        int o = tid;
        float acc[16];
        float bv = BB[BB_B2 + o];
        #pragma unroll
        for (int r=0;r<16;r++) acc[r] = bv;
        for (int i=0;i<64;i++){
            float w = b2f(WB[WB_W2 + i*256 + o]);
            #pragma unroll
            for (int r=0;r<16;r++) acc[r] += h1[r][i]*w;
        }
        for (int r=0;r<16;r++){
            float v = acc[r] > 0.f ? acc[r] : 0.f;
            h2g[(size_t)(row0+r)*256 + o] = __float2bfloat16(v);
        }
    }
}

// ---- MFMA GEMM (64x64 tile): C = A @ Wt^T + bias ----
// mode 0: bf16 store | 1: GELU bf16 | 2: outf = res + v | 3: relu -> out0(flag dtype) & xf = relu + PE
__global__ __launch_bounds__(256) void k_mgemm(
    const bf16* __restrict__ A, const bf16* __restrict__ Wt, const float* __restrict__ bias,
    bf16* outh, float* outf, const float* __restrict__ res, void* out0, const int* flagp,
    int K, int N, int mode)
{
    __shared__ short As[64*200];
    __shared__ short Bs[64*200];
    int tid = threadIdx.x;
    int w = tid >> 6, lane = tid & 63, q = lane >> 4, li = lane & 15;
    int m0 = blockIdx.x * 64, n0 = blockIdx.y * 64;
    const int f = flagp ? *flagp : 0;
    f32x4 acc[4];
    #pragma unroll
    for (int nt=0;nt<4;nt++) acc[nt] = (f32x4){0.f,0.f,0.f,0.f};
    int nkc = (K + 191) / 192;
    for (int kc = 0; kc < nkc; kc++){
        int kcw = K - kc*192; if (kcw > 192) kcw = 192;
        int vr = kcw >> 3;
        const bf16* Ab = A  + (size_t)m0*K + kc*192;
        const bf16* Bb = Wt + (size_t)n0*K + kc*192;
        for (int idx = tid; idx < 64*vr; idx += 256){
            int r = idx / vr, kv = idx - r*vr;
            *(short8*)&As[r*200 + kv*8] = *(const short8*)&Ab[(size_t)r*K + kv*8];
        }
        for (int idx = tid; idx < 64*vr; idx += 256){
            int r = idx / vr, kv = idx - r*vr;
            *(short8*)&Bs[r*200 + kv*8] = *(const short8*)&Bb[(size_t)r*K + kv*8];
        }
        __syncthreads();
        int kkn = kcw >> 5;
        for (int kk = 0; kk < kkn; kk++){
            int ko = kk*32 + q*8;
            short8 a = *(short8*)&As[(w*16+li)*200 + ko];
            #pragma unroll
            for (int nt = 0; nt < 4; nt++){
                short8 b = *(short8*)&Bs[(nt*16+li)*200 + ko];
                acc[nt] = __builtin_amdgcn_mfma_f32_16x16x32_bf16(a, b, acc[nt], 0, 0, 0);
            }
        }
        __syncthreads();
    }
    int rb = m0 + w*16 + q*4;
    #pragma unroll
    for (int nt = 0; nt < 4; nt++){
        int col = n0 + nt*16 + li;
        float bv = bias[col];
        #pragma unroll
        for (int p = 0; p < 4; p++){
            int row = rb + p;
            float v = acc[nt][p] + bv;
            size_t idx = (size_t)row*N + col;
            if (mode == 0) outh[idx] = __float2bfloat16(v);
            else if (mode == 1) outh[idx] = __float2bfloat16(0.5f*v*(1.f + erff(v*0.70710678118654752f)));
            else if (mode == 2) outf[idx] = v + res[idx];
            else {
                float r2 = v > 0.f ? v : 0.f;
                if (f) ((bf16*)out0)[idx] = __float2bfloat16(r2);
                else   ((float*)out0)[idx] = r2;
                int t = row % T_;
                int i2 = col & ~1;
                float dv = expf((float)i2 * (-9.210340371976184f/192.f));
                float ang = (float)t * dv;
                outf[idx] = r2 + ((col & 1) ? cosf(ang) : sinf(ang));
            }
        }
    }
}

// ---- MFMA GEMM (128x64 tile, K%96==0): mode 0 bf16 | 1 GELU bf16 | 4 fp16 ----
__global__ __launch_bounds__(256) void k_mgemm128(
    const bf16* __restrict__ A, const bf16* __restrict__ Wt, const float* __restrict__ bias,
    bf16* outh, int K, int N, int mode)
{
    __shared__ short As[128*104];
    __shared__ short Bs[64*104];
    int tid = threadIdx.x;
    int w = tid >> 6, lane = tid & 63, q = lane >> 4, li = lane & 15;
    int m0 = blockIdx.x * 128, n0 = blockIdx.y * 64;
    f32x4 acc[2][4];
    #pragma unroll
    for (int mt=0;mt<2;mt++)
        #pragma unroll
        for (int nt=0;nt<4;nt++) acc[mt][nt] = (f32x4){0.f,0.f,0.f,0.f};
    int nkc = K / 96;
    for (int kc = 0; kc < nkc; kc++){
        const bf16* Ab = A  + (size_t)m0*K + kc*96;
        const bf16* Bb = Wt + (size_t)n0*K + kc*96;
        for (int idx = tid; idx < 128*12; idx += 256){
            int r = idx / 12, kv = idx - r*12;
            *(short8*)&As[r*104 + kv*8] = *(const short8*)&Ab[(size_t)r*K + kv*8];
        }
        for (int idx = tid; idx < 64*12; idx += 256){
            int r = idx / 12, kv = idx - r*12;
            *(short8*)&Bs[r*104 + kv*8] = *(const short8*)&Bb[(size_t)r*K + kv*8];
        }
        __syncthreads();
        #pragma unroll
        for (int kk = 0; kk < 3; kk++){
            int ko = kk*32 + q*8;
            short8 b0 = *(short8*)&Bs[(0*16+li)*104 + ko];
            short8 b1 = *(short8*)&Bs[(1*16+li)*104 + ko];
            short8 b2 = *(short8*)&Bs[(2*16+li)*104 + ko];
            short8 b3 = *(short8*)&Bs[(3*16+li)*104 + ko];
            #pragma unroll
            for (int mt = 0; mt < 2; mt++){
                short8 a = *(short8*)&As[(w*32 + mt*16 + li)*104 + ko];
                acc[mt][0] = __builtin_amdgcn_mfma_f32_16x16x32_bf16(a, b0, acc[mt][0], 0, 0, 0);
                acc[mt][1] = __builtin_amdgcn_mfma_f32_16x16x32_bf16(a, b1, acc[mt][1], 0, 0, 0);
                acc[mt][2] = __builtin_amdgcn_mfma_f32_16x16x32_bf16(a, b2, acc[mt][2], 0, 0, 0);
                acc[mt][3] = __builtin_amdgcn_mfma_f32_16x16x32_bf16(a, b3, acc[mt][3], 0, 0, 0);
            }
        }
        __syncthreads();
    }
    #pragma unroll
    for (int mt = 0; mt < 2; mt++){
        int rb = m0 + w*32 + mt*16 + q*4;
        #pragma unroll
        for (int nt = 0; nt < 4; nt++){
            int col = n0 + nt*16 + li;
            float bv = bias[col];
            #pragma unroll
            for (int p = 0; p < 4; p++){
                float v = acc[mt][nt][p] + bv;
                size_t idx = (size_t)(rb+p)*N + col;
                if (mode == 0) outh[idx] = __float2bfloat16(v);
                else if (mode == 1) outh[idx] = __float2bfloat16(0.5f*v*(1.f + erff(v*0.70710678118654752f)));
                else ((_Float16*)outh)[idx] = (_Float16)v;
            }
        }
    }
}

// ---- LayerNorm (one wave per row), optional permute to node order ----
__global__ __launch_bounds__(256) void k_ln(const float* __restrict__ x, const void* g, const void* b,
                     size_t gOff, const int* flagp, bf16* out, int permute)
{
    const int f = *flagp;
    int tid = threadIdx.x;
    int row = blockIdx.x*4 + (tid>>6);
    int lane = tid & 63;
    const float* xr = x + (size_t)row*192;
    float v0 = xr[lane], v1 = xr[lane+64], v2 = xr[lane+128];
    float s = v0+v1+v2;
    float qq = v0*v0+v1*v1+v2*v2;
    #pragma unroll
    for (int off=32; off; off>>=1){ s += __shfl_xor(s, off); qq += __shfl_xor(qq, off); }
    float mean = s * (1.f/192.f);
    float var  = qq * (1.f/192.f) - mean*mean;
    float rs = rsqrtf(var + 1e-5f);
    int orow = row;
    if (permute){ int n = row/T_, t = row%T_; int bb = n/A_, a = n%A_; orow = (bb*T_+t)*A_ + a; }
    bf16* op = out + (size_t)orow*192;
    op[lane]     = __float2bfloat16((v0-mean)*rs*ldf(g,gOff+lane,f)     + ldf(b,gOff+lane,f));
    op[lane+64]  = __float2bfloat16((v1-mean)*rs*ldf(g,gOff+lane+64,f)  + ldf(b,gOff+lane+64,f));
    op[lane+128] = __float2bfloat16((v2-mean)*rs*ldf(g,gOff+lane+128,f) + ldf(b,gOff+lane+128,f));
}

// ---- causal attention, one wave per (seq, head, 16-query tile); online softmax ----
__global__ __launch_bounds__(64) void k_attn(bfp qkv, bf16* attn_o)
{
    __shared__ float Ks[80][32];
    __shared__ float Vs[80][32];
    int bid = blockIdx.x;
    int qt = bid % 5;
    int nh = bid / 5;
    int n = nh / H_, h = nh % H_;
    int tid = threadIdx.x;
    for (int idx = tid; idx < 640; idx += 64){
        int r = idx >> 3, c4 = (idx & 7) << 2;
        const bf16* rp = qkv + (size_t)(n*T_+r)*576 + h*32 + c4;
        short4v kv = *(const short4v*)(rp + 192);
        short4v vv = *(const short4v*)(rp + 384);
        f32x4 kf, vf;
        #pragma unroll
        for (int e=0;e<4;e++){
            kf[e] = __uint_as_float(((unsigned)(unsigned short)kv[e])<<16);
            vf[e] = __uint_as_float(((unsigned)(unsigned short)vv[e])<<16);
        }
        *(f32x4*)&Ks[r][c4] = kf;
        *(f32x4*)&Vs[r][c4] = vf;
    }
    __syncthreads();
    int qi = tid & 15, p = tid >> 4;
    int q = qt*16 + qi;
    float qv[8];
    const bf16* qp = qkv + (size_t)(n*T_+q)*576 + h*32 + p*8;
    #pragma unroll
    for (int c=0;c<8;c++) qv[c] = b2f(qp[c]);
    float m = -1e30f, l = 0.f;
    float acc[8];
    #pragma unroll
    for (int c=0;c<8;c++) acc[c]=0.f;
    int jmax = qt*16 + 15;
    for (int j = 0; j <= jmax; j++){
        float s = 0.f;
        #pragma unroll
        for (int c=0;c<8;c++) s += qv[c]*Ks[j][p*8+c];
        s += __shfl_xor(s, 16);
        s += __shfl_xor(s, 32);
        s *= 0.17677669529663687f;
        if (j > q) s = -1e30f;
        float mn = fmaxf(m, s);
        float corr = expf(m - mn);
        float e = expf(s - mn);
        l = l*corr + e;
        #pragma unroll
        for (int c=0;c<8;c++) acc[c] = acc[c]*corr + e*Vs[j][p*8+c];
        m = mn;
    }
    float inv = 1.f/l;
    bf16* op = attn_o + (size_t)(n*T_+q)*192 + h*32 + p*8;
    #pragma unroll
    for (int c=0;c<8;c++) op[c] = __float2bfloat16(acc[c]*inv);
}

// ---- self-loop attr = mean of incoming edge attrs; one block per graph ----
__global__ __launch_bounds__(192) void k_loopea(const int* __restrict__ eidx, const void* ea,
                                                const int* flagp, float* lea)
{
    __shared__ float s0[A_], s1[A_];
    __shared__ int cnt[A_];
    const int f = *flagp;
    int g = blockIdx.x;
    int tid = threadIdx.x;
    if (tid < A_){ s0[tid] = 0.f; s1[tid] = 0.f; cnt[tid] = 0; }
    __syncthreads();
    if (tid < E_){
        int d = eidx[E_ + tid];
        float a0 = ldf(ea, (size_t)(g*E_+tid)*2,   f);
        float a1 = ldf(ea, (size_t)(g*E_+tid)*2+1, f);
        atomicAdd(&s0[d], a0);
        atomicAdd(&s1[d], a1);
        atomicAdd(&cnt[d], 1);
    }
    __syncthreads();
    if (tid < A_){
        int c = cnt[tid] < 1 ? 1 : cnt[tid];
        lea[(g*A_+tid)*2]   = s0[tid]/(float)c;
        lea[(g*A_+tid)*2+1] = s1[tid]/(float)c;
    }
}

// ---- GAT edge logits: one wave per (g, d, 4 sources); round-13 inner math.
// Wave caches xr[d] + weight strips once, loops s = sg*4..sg*4+3.
// XCD-swizzled: 9 blocks (36 waves) per graph on one XCD.
// alpha layout: [(g*12+d)*12+s][H]. leaky via 0.6*m + 0.4*|m|, single fdot2.
__global__ __launch_bounds__(256) void k_alpha(const _Float16* __restrict__ xlr,
                        const float* __restrict__ lea, const void* ea,
                        const _Float16* __restrict__ gweh, const _Float16* __restrict__ gatth,
                        const int* flagp, float* alpha)
{
    const int f = *flagp;
    int bid = blockIdx.x;                    // 5760 blocks
    int xcd = bid & 7, slot = bid >> 3;      // 720 slots per XCD
    int g = xcd*80 + slot/9;                 // 80 graphs per XCD
    int unit = (slot % 9)*4 + (threadIdx.x>>6);   // 0..35
    int d = unit / 3, sg = unit % 3;
    int lane = threadIdx.x & 63;
    int co = 6*lane;
    const h2 c06 = (h2){(_Float16)0.6f, (_Float16)0.6f};
    const h2 c04 = (h2){(_Float16)0.4f, (_Float16)0.4f};
    // hoisted: xr[d] strips + weight strips (identical across the 4 edges)
    h2 xr[9], g0[9], g1[9], ga[9];
    const _Float16* xrd = xlr + (size_t)(g*A_+d)*2304 + 1152;
    #pragma unroll
    for (int hg = 0; hg < 3; hg++)
        #pragma unroll
        for (int j = 0; j < 3; j++){
            int o = hg*384 + co + 2*j;
            int i = hg*3 + j;
            xr[i] = *(const h2*)(xrd + o);
            g0[i] = *(const h2*)(gweh + o);
            g1[i] = *(const h2*)(gweh + 1152 + o);
            ga[i] = *(const h2*)(gatth + o);
        }
    for (int si = 0; si < 4; si++){
        int s = sg*4 + si;
        float f0, f1;
        if (s == d){
            f0 = lea[(g*A_+s)*2]; f1 = lea[(g*A_+s)*2+1];
        } else {
            int el = s*11 + (d < s ? d : d-1);
            f0 = ldf(ea, (size_t)(g*E_+el)*2,   f);
            f1 = ldf(ea, (size_t)(g*E_+el)*2+1, f);
        }
        h2 f0h = (h2){(_Float16)f0, (_Float16)f0};
        h2 f1h = (h2){(_Float16)f1, (_Float16)f1};
        const _Float16* xls = xlr + (size_t)(g*A_+s)*2304;
        float* ap = alpha + ((size_t)(g*A_+d)*12 + s)*H_;
        #pragma unroll
        for (int hg = 0; hg < 3; hg++){
            float p = 0.f;
            #pragma unroll
            for (int j = 0; j < 3; j++){
                int o = hg*384 + co + 2*j;
                int i = hg*3 + j;
                h2 xl2 = *(const h2*)(xls + o);
                h2 m = xl2 + xr[i];
                m = g0[i]*f0h + m;
                m = g1[i]*f1h + m;
                unsigned mu = __builtin_bit_cast(unsigned, m) & 0x7fff7fffu;
                h2 am = __builtin_bit_cast(h2, mu);
                h2 q = m*c06 + am*c04;
                p = __builtin_amdgcn_fdot2(ga[i], q, p, false);
            }
            #pragma unroll
            for (int off=1; off<32; off<<=1) p += __shfl_xor(p, off);
            if ((lane & 31) == 0)
                ap[hg*2 + (lane>>5)] = p;
        }
    }
}

// ---- GAT segment softmax + aggregate; XCD-swizzled; optional final-output store ----
__global__ __launch_bounds__(192) void k_segagg(const _Float16* __restrict__ xlr,
                         const float* __restrict__ alpha,
                         const void* gbias, size_t gbOff, const int* flagp, float* xf,
                         void* out)
{
    __shared__ float al[12][6];
    __shared__ float w[12][6];
    const int f = *flagp;
    int bid = blockIdx.x;
    int xcd = bid & 7, slot = bid >> 3;
    int gl = xcd*80 + slot/12;
    int a = slot % 12;
    int node = gl*A_ + a;
    int tid = threadIdx.x;
    if (tid < 72) ((float*)al)[tid] = alpha[(size_t)node*72 + tid];
    __syncthreads();
    if (tid < 6){
        float m = -1e30f;
        #pragma unroll
        for (int s=0;s<12;s++) m = fmaxf(m, al[s][tid]);
        float den = 0.f;
        #pragma unroll
        for (int s=0;s<12;s++){ float ex = expf(al[s][tid]-m); w[s][tid] = ex; den += ex; }
        float inv = 1.f/den;
        #pragma unroll
        for (int s=0;s<12;s++) w[s][tid] *= inv;
    }
    __syncthreads();
    int c = tid;
    float acc = 0.f;
    for (int s=0;s<12;s++){
        const _Float16* xp = xlr + (size_t)(gl*A_ + s)*2304 + c;
        #pragma unroll
        for (int h=0;h<6;h++) acc += w[s][h]*(float)xp[h*192];
    }
    int b = gl / T_, t = gl % T_;
    int xrow = (b*A_ + a)*T_ + t;
    size_t idx = (size_t)xrow*192 + c;
    float newv = xf[idx] + acc*(1.f/6.f) + ldf(gbias, gbOff + c, f);
    xf[idx] = newv;
    if (out){
        if (f) ((bf16*)out)[1474560 + idx] = __float2bfloat16(newv);
        else   ((float*)out)[1474560 + idx] = newv;
    }
}

extern "C" void kernel_launch(void* const* d_in, const int* in_sizes, int n_in,
                              void* d_out, int out_size, void* d_ws, size_t ws_size,
                              hipStream_t stream)
{
    const void* sf   = d_in[0];
    const int* ids  = (const int*)d_in[2];
    const int* eidx = (const int*)d_in[3];
    const void* ea   = d_in[4];
    const void* emb  = d_in[5];
    const void *laW1=d_in[6],  *lab1=d_in[7];
    const void *bn1g=d_in[8],  *bn1b=d_in[9],  *bn1m=d_in[10], *bn1v=d_in[11];
    const void *laW2=d_in[12], *lab2=d_in[13];
    const void *bn2g=d_in[14], *bn2b=d_in[15], *bn2m=d_in[16], *bn2v=d_in[17];
    const void *laW3=d_in[18], *lab3=d_in[19];
    const void *bn3g=d_in[20], *bn3b=d_in[21], *bn3m=d_in[22], *bn3v=d_in[23];
    const void *ln1g=d_in[24], *ln1b=d_in[25];
    const void *qkvw=d_in[26], *qkvb=d_in[27];
    const void *outw=d_in[28], *outb=d_in[29];
    const void *ln2g=d_in[30], *ln2b=d_in[31];
    const void *fw1 =d_in[32], *fb1 =d_in[33];
    const void *fw2 =d_in[34], *fb2 =d_in[35];
    const void *gwl =d_in[36], *gbl =d_in[37];
    const void *gwr =d_in[38], *gbr =d_in[39];
    const void *gwe =d_in[40];
    const void *gatt=d_in[41];
    const void *gbias=d_in[42];
    const void *ng  =d_in[43], *nb  =d_in[44];

    float* ws = (float*)d_ws;
    float* xf  = ws;                          // [0, 1474560)
    bf16*  xn  = (bf16*)(ws + 1474560);       // 1,474,560 bf16
    bf16*  qkv = (bf16*)(ws + 2211840);       // 4,423,680 bf16
    bf16*  ao  = (bf16*)(ws + 4423680);       // 1,474,560 bf16
    bf16*  hb  = (bf16*)(ws + 2211840);       // overlays qkv+ao (FFN hidden)
    bf16*  h2g = (bf16*)(ws + 2211840);       // overlays (MLP hidden)
    bf16*  xlr = (bf16*)(ws + 2211840);       // overlays (GAT full lr: 17,694,720 fp16)
    float* lea = ws + 11059200;               // 15,360
    int*  flag = (int*)(ws + 11074560);
    bf16*  WB  = (bf16*)(ws + 11074568);      // 2,731,136 x 2B
    float* BB  = ws + 12440136;               // 12,608 f32
    float* alp = ws + 12452744;               // 552,960 f32 (dense [node][src][head])
    (void)ws_size; (void)in_sizes; (void)n_in; (void)out_size;

    k_detect<<<1, 1, 0, stream>>>(sf, flag);
    k_convert<<<(WB_TOT+BB_TOT+255)/256, 256, 0, stream>>>(
        qkvw, outw, fw1, fw2, gwl, gwr, gwe, gatt,
        laW1, lab1, bn1g, bn1b, bn1m, bn1v,
        laW2, lab2, bn2g, bn2b, bn2m, bn2v,
        laW3, lab3, bn3g, bn3b, bn3m, bn3v,
        qkvb, outb, fb1, fb2, gbl, gbr, flag, WB, BB);
    k_mlp_a<<<ROWS_/16, 256, 0, stream>>>(sf, ids, emb, flag, WB, BB, h2g);
    k_mgemm<<<dim3(ROWS_/64, 3), 256, 0, stream>>>(h2g, WB + WB_W3T, BB + BB_B3,
        nullptr, xf, nullptr, d_out, flag, 256, 192, 3);
    k_loopea<<<G_, 192, 0, stream>>>(eidx, ea, flag, lea);

    for (int l=0; l<3; l++){
        k_ln<<<ROWS_/4, 256, 0, stream>>>(xf, ln1g, ln1b, (size_t)l*192, flag, xn, 0);
        k_mgemm128<<<dim3(ROWS_/128, 9), 256, 0, stream>>>(xn, WB + WB_QKV + (size_t)l*110592,
            BB + BB_QKV + l*576, qkv, 192, 576, 0);
        k_attn<<<N_*H_*5, 64, 0, stream>>>(qkv, ao);
        k_mgemm<<<dim3(ROWS_/64, 3), 256, 0, stream>>>(ao, WB + WB_OUT + (size_t)l*36864,
            BB + BB_OUT + l*192, nullptr, xf, xf, nullptr, nullptr, 192, 192, 2);
        k_ln<<<ROWS_/4, 256, 0, stream>>>(xf, ln2g, ln2b, (size_t)l*192, flag, xn, 0);
        k_mgemm128<<<dim3(ROWS_/128, 12), 256, 0, stream>>>(xn, WB + WB_FW1 + (size_t)l*147456,
            BB + BB_FW1 + l*768, hb, 192, 768, 1);
        k_mgemm<<<dim3(ROWS_/64, 3), 256, 0, stream>>>(hb, WB + WB_FW2 + (size_t)l*147456,
            BB + BB_FW2 + l*192, nullptr, xf, xf, nullptr, nullptr, 768, 192, 2);
        k_ln<<<ROWS_/4, 256, 0, stream>>>(xf, ng, nb, (size_t)l*192, flag, xn, 1);
        k_mgemm128<<<dim3(ROWS_/128, 36), 256, 0, stream>>>(xn, WB + WB_GAT + (size_t)l*442368,
            BB + BB_GAT + l*2304, xlr, 192, 2304, 4);
        k_alpha<<<G_*36/4, 256, 0, stream>>>((const _Float16*)xlr, lea, ea,
            (const _Float16*)(WB + WB_GWE) + (size_t)l*2304,
            (const _Float16*)(WB + WB_GATT) + (size_t)l*1152, flag, alp);
        k_segagg<<<G_*A_, 192, 0, stream>>>((const _Float16*)xlr, alp, gbias, (size_t)l*192, flag, xf,
            l == 2 ? d_out : nullptr);
    }
}

// Round 16
// 795.699 us; speedup vs baseline: 1.1289x; 1.0178x over previous
//
#include <hip/hip_runtime.h>
#include <hip/hip_bf16.h>
#include <math.h>

#define A_   12
#define H_   6
#define N_   96
#define T_   80
#define G_   640
#define E_   132
#define E2_  144
#define ROWS_ 7680

typedef const __hip_bfloat16* bfp;
typedef __hip_bfloat16 bf16;
typedef __attribute__((ext_vector_type(8))) short short8;
typedef __attribute__((ext_vector_type(4))) short short4v;
typedef __attribute__((ext_vector_type(4))) float f32x4;
typedef _Float16 h2 __attribute__((ext_vector_type(2)));

// ---- weight arena element offsets (in 2-byte units) ----
#define WB_QKV   0                /* [3][576][192]  */
#define WB_OUT   331776           /* [3][192][192]  */
#define WB_FW1   442368           /* [3][768][192]  */
#define WB_FW2   884736           /* [3][192][768]  */
#define WB_GAT   1327104          /* [3][2304][192] (gwl|gwr) */
#define WB_W1    2654208          /* [16][64] BN-folded */
#define WB_W2    2655232          /* [64][256] BN-folded */
#define WB_W3T   2671616          /* [192][256] BN-folded, transposed */
#define WB_GWE   2720768          /* [3][2304]  (fp16) */
#define WB_GATT  2727680          /* [3][1152]  (fp16) */
#define WB_TOT   2731136
// ---- f32 bias arena element offsets ----
#define BB_QKV   0
#define BB_OUT   1728
#define BB_FW1   2304
#define BB_FW2   4608
#define BB_GAT   5184
#define BB_B1    12096
#define BB_B2    12160
#define BB_B3    12416
#define BB_TOT   12608

__device__ __forceinline__ float b2f(bf16 x){ return __bfloat162float(x); }
__device__ __forceinline__ float ldf(const void* p, size_t i, int f){
    return f ? __bfloat162float(((const bf16*)p)[i]) : ((const float*)p)[i];
}

// dtype probe: even uint16s of f32 storage are random mantissa halves.
__global__ void k_detect(const void* sf, int* flag)
{
    const unsigned short* u = (const unsigned short*)sf;
    int sane = 0;
    for (int i = 0; i < 64; i++){
        unsigned short v = u[2*i];
        int e = (v >> 7) & 0xFF;
        if (e == 0 || (e >= 100 && e <= 140)) sane++;
    }
    *flag = (sane >= 48) ? 1 : 0;
}

// ---- convert+transpose all weights into arena (bf16; gwe/gatt fp16); biases f32 ----
__global__ __launch_bounds__(256) void k_convert(
    const void* qkvw, const void* outw, const void* fw1, const void* fw2,
    const void* gwl, const void* gwr, const void* gwe, const void* gatt,
    const void* W1, const void* b1, const void* g1, const void* be1, const void* m1, const void* v1,
    const void* W2, const void* b2, const void* g2, const void* be2, const void* m2, const void* v2,
    const void* W3, const void* b3, const void* g3, const void* be3, const void* m3, const void* v3,
    const void* qkvb, const void* outb, const void* fb1, const void* fb2,
    const void* gbl, const void* gbr,
    const int* flagp, bf16* WB, float* BB)
{
    const int f = *flagp;
    size_t idx = (size_t)blockIdx.x*256 + threadIdx.x;
    if (idx < WB_TOT){
        float v; int ishalf = 0;
        if (idx < WB_OUT){            size_t i=idx-WB_QKV; int l=i/110592; int r=i%110592; int n=r/192, k=r%192;
            v = ldf(qkvw, (size_t)l*110592 + (size_t)k*576 + n, f);
        } else if (idx < WB_FW1){     size_t i=idx-WB_OUT; int l=i/36864; int r=i%36864; int n=r/192, k=r%192;
            v = ldf(outw, (size_t)l*36864 + (size_t)k*192 + n, f);
        } else if (idx < WB_FW2){     size_t i=idx-WB_FW1; int l=i/147456; int r=i%147456; int n=r/192, k=r%192;
            v = ldf(fw1, (size_t)l*147456 + (size_t)k*768 + n, f);
        } else if (idx < WB_GAT){     size_t i=idx-WB_FW2; int l=i/147456; int r=i%147456; int n=r/768, k=r%768;
            v = ldf(fw2, (size_t)l*147456 + (size_t)k*192 + n, f);
        } else if (idx < WB_W1){      size_t i=idx-WB_GAT; int l=i/442368; int r=i%442368; int n=r/192, k=r%192;
            if (n < 1152) v = ldf(gwl, (size_t)l*221184 + (size_t)k*1152 + n, f);
            else          v = ldf(gwr, (size_t)l*221184 + (size_t)k*1152 + (n-1152), f);
        } else if (idx < WB_W2){      size_t i=idx-WB_W1; int o=i%64;
            float s = ldf(g1,o,f)*rsqrtf(ldf(v1,o,f)+1e-5f);
            v = ldf(W1, i, f) * s;
        } else if (idx < WB_W3T){     size_t i=idx-WB_W2; int o=i%256;
            float s = ldf(g2,o,f)*rsqrtf(ldf(v2,o,f)+1e-5f);
            v = ldf(W2, i, f) * s;
        } else if (idx < WB_GWE){     size_t i=idx-WB_W3T; int n=i/256, k=i%256;
            float s = ldf(g3,n,f)*rsqrtf(ldf(v3,n,f)+1e-5f);
            v = ldf(W3, (size_t)k*192 + n, f) * s;
        } else if (idx < WB_GATT){    size_t i=idx-WB_GWE;
            v = ldf(gwe, i, f); ishalf = 1;
        } else {                      size_t i=idx-WB_GATT;
            v = ldf(gatt, i, f); ishalf = 1;
        }
        if (ishalf) ((_Float16*)WB)[idx] = (_Float16)v;
        else        WB[idx] = __float2bfloat16(v);
    } else if (idx < WB_TOT + BB_TOT){
        size_t j = idx - WB_TOT;
        float v;
        if (j < BB_OUT)        v = ldf(qkvb, j, f);
        else if (j < BB_FW1)   v = ldf(outb, j-BB_OUT, f);
        else if (j < BB_FW2)   v = ldf(fb1, j-BB_FW1, f);
        else if (j < BB_GAT)   v = ldf(fb2, j-BB_FW2, f);
        else if (j < BB_B1){   size_t i=j-BB_GAT; int l=i/2304; int o=i%2304;
            v = (o<1152) ? ldf(gbl, (size_t)l*1152+o, f) : ldf(gbr, (size_t)l*1152+o-1152, f);
        } else if (j < BB_B2){ int o=j-BB_B1;
            float s = ldf(g1,o,f)*rsqrtf(ldf(v1,o,f)+1e-5f);
            v = (ldf(b1,o,f)-ldf(m1,o,f))*s + ldf(be1,o,f);
        } else if (j < BB_B3){ int o=j-BB_B2;
            float s = ldf(g2,o,f)*rsqrtf(ldf(v2,o,f)+1e-5f);
            v = (ldf(b2,o,f)-ldf(m2,o,f))*s + ldf(be2,o,f);
        } else {               int o=j-BB_B3;
            float s = ldf(g3,o,f)*rsqrtf(ldf(v3,o,f)+1e-5f);
            v = (ldf(b3,o,f)-ldf(m3,o,f))*s + ldf(be3,o,f);
        }
        BB[j] = v;
    }
}

// ---- MLP stages 1+2: in16 -> 64 -> 256 (relu, BN folded), 16 rows/block ----
__global__ __launch_bounds__(256) void k_mlp_a(
    const void* sf, const int* ids, const void* emb, const int* flagp,
    const bf16* __restrict__ WB, const float* __restrict__ BB, bf16* h2g)
{
    __shared__ float in16[16][16];
    __shared__ float h1[16][64];
    const int f = *flagp;
    int tid = threadIdx.x;
    int row0 = blockIdx.x * 16;
    {
        int r = tid >> 4, i = tid & 15;
        int row = row0 + r;
        float v;
        if (i < 4) v = ldf(sf, (size_t)row*4 + i, f);
        else {
            int id = ids[row / T_]; if (id < 0) id = 0; if (id > 599) id = 599;
            v = ldf(emb, (size_t)id*12 + (i-4), f);
        }
        in16[r][i] = v;
    }
    __syncthreads();
    {
        int o = tid & 63, rg = tid >> 6;
        float acc[4];
        float bv = BB[BB_B1 + o];
        #pragma unroll
        for (int j=0;j<4;j++) acc[j] = bv;
        for (int i=0;i<16;i++){
            float w = b2f(WB[WB_W1 + i*64 + o]);
            #pragma unroll
            for (int j=0;j<4;j++) acc[j] += in16[rg*4+j][i]*w;
        }
        #pragma unroll
        for (int j=0;j<4;j++) h1[rg*4+j][o] = acc[j] > 0.f ? acc[j] : 0.f;
    }
    __syncthreads();
    {
        int o = tid;
        float acc[16];
        float bv = BB[BB_B2 + o];
        #pragma unroll
        for (int r=0;r<16;r++) acc[r] = bv;
        for (int i=0;i<64;i++){
            float w = b2f(WB[WB_W2 + i*256 + o]);
            #pragma unroll
            for (int r=0;r<16;r++) acc[r] += h1[r][i]*w;
        }
        for (int r=0;r<16;r++){
            float v = acc[r] > 0.f ? acc[r] : 0.f;
            h2g[(size_t)(row0+r)*256 + o] = __float2bfloat16(v);
        }
    }
}

// ---- MFMA GEMM (64x64 tile): C = A @ Wt^T + bias ----
// mode 0: bf16 store | 1: GELU bf16 | 2: outf = res + v | 3: relu -> out0(flag dtype) & xf = relu + PE
__global__ __launch_bounds__(256) void k_mgemm(
    const bf16* __restrict__ A, const bf16* __restrict__ Wt, const float* __restrict__ bias,
    bf16* outh, float* outf, const float* __restrict__ res, void* out0, const int* flagp,
    int K, int N, int mode)
{
    __shared__ short As[64*200];
    __shared__ short Bs[64*200];
    int tid = threadIdx.x;
    int w = tid >> 6, lane = tid & 63, q = lane >> 4, li = lane & 15;
    int m0 = blockIdx.x * 64, n0 = blockIdx.y * 64;
    const int f = flagp ? *flagp : 0;
    f32x4 acc[4];
    #pragma unroll
    for (int nt=0;nt<4;nt++) acc[nt] = (f32x4){0.f,0.f,0.f,0.f};
    int nkc = (K + 191) / 192;
    for (int kc = 0; kc < nkc; kc++){
        int kcw = K - kc*192; if (kcw > 192) kcw = 192;
        int vr = kcw >> 3;
        const bf16* Ab = A  + (size_t)m0*K + kc*192;
        const bf16* Bb = Wt + (size_t)n0*K + kc*192;
        for (int idx = tid; idx < 64*vr; idx += 256){
            int r = idx / vr, kv = idx - r*vr;
            *(short8*)&As[r*200 + kv*8] = *(const short8*)&Ab[(size_t)r*K + kv*8];
        }
        for (int idx = tid; idx < 64*vr; idx += 256){
            int r = idx / vr, kv = idx - r*vr;
            *(short8*)&Bs[r*200 + kv*8] = *(const short8*)&Bb[(size_t)r*K + kv*8];
        }
        __syncthreads();
        int kkn = kcw >> 5;
        for (int kk = 0; kk < kkn; kk++){
            int ko = kk*32 + q*8;
            short8 a = *(short8*)&As[(w*16+li)*200 + ko];
            #pragma unroll
            for (int nt = 0; nt < 4; nt++){
                short8 b = *(short8*)&Bs[(nt*16+li)*200 + ko];
                acc[nt] = __builtin_amdgcn_mfma_f32_16x16x32_bf16(a, b, acc[nt], 0, 0, 0);
            }
        }
        __syncthreads();
    }
    int rb = m0 + w*16 + q*4;
    #pragma unroll
    for (int nt = 0; nt < 4; nt++){
        int col = n0 + nt*16 + li;
        float bv = bias[col];
        #pragma unroll
        for (int p = 0; p < 4; p++){
            int row = rb + p;
            float v = acc[nt][p] + bv;
            size_t idx = (size_t)row*N + col;
            if (mode == 0) outh[idx] = __float2bfloat16(v);
            else if (mode == 1) outh[idx] = __float2bfloat16(0.5f*v*(1.f + erff(v*0.70710678118654752f)));
            else if (mode == 2) outf[idx] = v + res[idx];
            else {
                float r2 = v > 0.f ? v : 0.f;
                if (f) ((bf16*)out0)[idx] = __float2bfloat16(r2);
                else   ((float*)out0)[idx] = r2;
                int t = row % T_;
                int i2 = col & ~1;
                float dv = expf((float)i2 * (-9.210340371976184f/192.f));
                float ang = (float)t * dv;
                outf[idx] = r2 + ((col & 1) ? cosf(ang) : sinf(ang));
            }
        }
    }
}

// ---- MFMA GEMM (128x64 tile, K%96==0): mode 0 bf16 | 1 GELU bf16 | 4 fp16 ----
__global__ __launch_bounds__(256) void k_mgemm128(
    const bf16* __restrict__ A, const bf16* __restrict__ Wt, const float* __restrict__ bias,
    bf16* outh, int K, int N, int mode)
{
    __shared__ short As[128*104];
    __shared__ short Bs[64*104];
    int tid = threadIdx.x;
    int w = tid >> 6, lane = tid & 63, q = lane >> 4, li = lane & 15;
    int m0 = blockIdx.x * 128, n0 = blockIdx.y * 64;
    f32x4 acc[2][4];
    #pragma unroll
    for (int mt=0;mt<2;mt++)
        #pragma unroll
        for (int nt=0;nt<4;nt++) acc[mt][nt] = (f32x4){0.f,0.f,0.f,0.f};
    int nkc = K / 96;
    for (int kc = 0; kc < nkc; kc++){
        const bf16* Ab = A  + (size_t)m0*K + kc*96;
        const bf16* Bb = Wt + (size_t)n0*K + kc*96;
        for (int idx = tid; idx < 128*12; idx += 256){
            int r = idx / 12, kv = idx - r*12;
            *(short8*)&As[r*104 + kv*8] = *(const short8*)&Ab[(size_t)r*K + kv*8];
        }
        for (int idx = tid; idx < 64*12; idx += 256){
            int r = idx / 12, kv = idx - r*12;
            *(short8*)&Bs[r*104 + kv*8] = *(const short8*)&Bb[(size_t)r*K + kv*8];
        }
        __syncthreads();
        #pragma unroll
        for (int kk = 0; kk < 3; kk++){
            int ko = kk*32 + q*8;
            short8 b0 = *(short8*)&Bs[(0*16+li)*104 + ko];
            short8 b1 = *(short8*)&Bs[(1*16+li)*104 + ko];
            short8 b2 = *(short8*)&Bs[(2*16+li)*104 + ko];
            short8 b3 = *(short8*)&Bs[(3*16+li)*104 + ko];
            #pragma unroll
            for (int mt = 0; mt < 2; mt++){
                short8 a = *(short8*)&As[(w*32 + mt*16 + li)*104 + ko];
                acc[mt][0] = __builtin_amdgcn_mfma_f32_16x16x32_bf16(a, b0, acc[mt][0], 0, 0, 0);
                acc[mt][1] = __builtin_amdgcn_mfma_f32_16x16x32_bf16(a, b1, acc[mt][1], 0, 0, 0);
                acc[mt][2] = __builtin_amdgcn_mfma_f32_16x16x32_bf16(a, b2, acc[mt][2], 0, 0, 0);
                acc[mt][3] = __builtin_amdgcn_mfma_f32_16x16x32_bf16(a, b3, acc[mt][3], 0, 0, 0);
            }
        }
        __syncthreads();
    }
    #pragma unroll
    for (int mt = 0; mt < 2; mt++){
        int rb = m0 + w*32 + mt*16 + q*4;
        #pragma unroll
        for (int nt = 0; nt < 4; nt++){
            int col = n0 + nt*16 + li;
            float bv = bias[col];
            #pragma unroll
            for (int p = 0; p < 4; p++){
                float v = acc[mt][nt][p] + bv;
                size_t idx = (size_t)(rb+p)*N + col;
                if (mode == 0) outh[idx] = __float2bfloat16(v);
                else if (mode == 1) outh[idx] = __float2bfloat16(0.5f*v*(1.f + erff(v*0.70710678118654752f)));
                else ((_Float16*)outh)[idx] = (_Float16)v;
            }
        }
    }
}

// ---- LayerNorm (one wave per row), optional permute to node order ----
__global__ __launch_bounds__(256) void k_ln(const float* __restrict__ x, const void* g, const void* b,
                     size_t gOff, const int* flagp, bf16* out, int permute)
{
    const int f = *flagp;
    int tid = threadIdx.x;
    int row = blockIdx.x*4 + (tid>>6);
    int lane = tid & 63;
    const float* xr = x + (size_t)row*192;
    float v0 = xr[lane], v1 = xr[lane+64], v2 = xr[lane+128];
    float s = v0+v1+v2;
    float qq = v0*v0+v1*v1+v2*v2;
    #pragma unroll
    for (int off=32; off; off>>=1){ s += __shfl_xor(s, off); qq += __shfl_xor(qq, off); }
    float mean = s * (1.f/192.f);
    float var  = qq * (1.f/192.f) - mean*mean;
    float rs = rsqrtf(var + 1e-5f);
    int orow = row;
    if (permute){ int n = row/T_, t = row%T_; int bb = n/A_, a = n%A_; orow = (bb*T_+t)*A_ + a; }
    bf16* op = out + (size_t)orow*192;
    op[lane]     = __float2bfloat16((v0-mean)*rs*ldf(g,gOff+lane,f)     + ldf(b,gOff+lane,f));
    op[lane+64]  = __float2bfloat16((v1-mean)*rs*ldf(g,gOff+lane+64,f)  + ldf(b,gOff+lane+64,f));
    op[lane+128] = __float2bfloat16((v2-mean)*rs*ldf(g,gOff+lane+128,f) + ldf(b,gOff+lane+128,f));
}

// ---- causal attention: one block per (seq, head); 5 waves share K/V LDS,
// wave qt handles queries qt*16..qt*16+15 with online softmax ----
__global__ __launch_bounds__(320) void k_attn(bfp qkv, bf16* attn_o)
{
    __shared__ float Ks[80][32];
    __shared__ float Vs[80][32];
    int nh = blockIdx.x;
    int n = nh / H_, h = nh % H_;
    int tid = threadIdx.x;
    for (int idx = tid; idx < 640; idx += 320){
        int r = idx >> 3, c4 = (idx & 7) << 2;
        const bf16* rp = qkv + (size_t)(n*T_+r)*576 + h*32 + c4;
        short4v kv = *(const short4v*)(rp + 192);
        short4v vv = *(const short4v*)(rp + 384);
        f32x4 kf, vf;
        #pragma unroll
        for (int e=0;e<4;e++){
            kf[e] = __uint_as_float(((unsigned)(unsigned short)kv[e])<<16);
            vf[e] = __uint_as_float(((unsigned)(unsigned short)vv[e])<<16);
        }
        *(f32x4*)&Ks[r][c4] = kf;
        *(f32x4*)&Vs[r][c4] = vf;
    }
    __syncthreads();
    int qt = tid >> 6;
    int lane = tid & 63;
    int qi = lane & 15, p = lane >> 4;
    int q = qt*16 + qi;
    float qv[8];
    const bf16* qp = qkv + (size_t)(n*T_+q)*576 + h*32 + p*8;
    #pragma unroll
    for (int c=0;c<8;c++) qv[c] = b2f(qp[c]);
    float m = -1e30f, l = 0.f;
    float acc[8];
    #pragma unroll
    for (int c=0;c<8;c++) acc[c]=0.f;
    int jmax = qt*16 + 15;
    for (int j = 0; j <= jmax; j++){
        float s = 0.f;
        #pragma unroll
        for (int c=0;c<8;c++) s += qv[c]*Ks[j][p*8+c];
        s += __shfl_xor(s, 16);
        s += __shfl_xor(s, 32);
        s *= 0.17677669529663687f;
        if (j > q) s = -1e30f;
        float mn = fmaxf(m, s);
        float corr = expf(m - mn);
        float e = expf(s - mn);
        l = l*corr + e;
        #pragma unroll
        for (int c=0;c<8;c++) acc[c] = acc[c]*corr + e*Vs[j][p*8+c];
        m = mn;
    }
    float inv = 1.f/l;
    bf16* op = attn_o + (size_t)(n*T_+q)*192 + h*32 + p*8;
    #pragma unroll
    for (int c=0;c<8;c++) op[c] = __float2bfloat16(acc[c]*inv);
}

// ---- self-loop attr = mean of incoming edge attrs; one block per graph ----
__global__ __launch_bounds__(192) void k_loopea(const int* __restrict__ eidx, const void* ea,
                                                const int* flagp, float* lea)
{
    __shared__ float s0[A_], s1[A_];
    __shared__ int cnt[A_];
    const int f = *flagp;
    int g = blockIdx.x;
    int tid = threadIdx.x;
    if (tid < A_){ s0[tid] = 0.f; s1[tid] = 0.f; cnt[tid] = 0; }
    __syncthreads();
    if (tid < E_){
        int d = eidx[E_ + tid];
        float a0 = ldf(ea, (size_t)(g*E_+tid)*2,   f);
        float a1 = ldf(ea, (size_t)(g*E_+tid)*2+1, f);
        atomicAdd(&s0[d], a0);
        atomicAdd(&s1[d], a1);
        atomicAdd(&cnt[d], 1);
    }
    __syncthreads();
    if (tid < A_){
        int c = cnt[tid] < 1 ? 1 : cnt[tid];
        lea[(g*A_+tid)*2]   = s0[tid]/(float)c;
        lea[(g*A_+tid)*2+1] = s1[tid]/(float)c;
    }
}

// ---- GAT edge logits: one wave per (g, d, 4 sources); XCD-swizzled ----
__global__ __launch_bounds__(256) void k_alpha(const _Float16* __restrict__ xlr,
                        const float* __restrict__ lea, const void* ea,
                        const _Float16* __restrict__ gweh, const _Float16* __restrict__ gatth,
                        const int* flagp, float* alpha)
{
    const int f = *flagp;
    int bid = blockIdx.x;
    int xcd = bid & 7, slot = bid >> 3;
    int g = xcd*80 + slot/9;
    int unit = (slot % 9)*4 + (threadIdx.x>>6);
    int d = unit / 3, sg = unit % 3;
    int lane = threadIdx.x & 63;
    int co = 6*lane;
    const h2 c06 = (h2){(_Float16)0.6f, (_Float16)0.6f};
    const h2 c04 = (h2){(_Float16)0.4f, (_Float16)0.4f};
    h2 xr[9], g0[9], g1[9], ga[9];
    const _Float16* xrd = xlr + (size_t)(g*A_+d)*2304 + 1152;
    #pragma unroll
    for (int hg = 0; hg < 3; hg++)
        #pragma unroll
        for (int j = 0; j < 3; j++){
            int o = hg*384 + co + 2*j;
            int i = hg*3 + j;
            xr[i] = *(const h2*)(xrd + o);
            g0[i] = *(const h2*)(gweh + o);
            g1[i] = *(const h2*)(gweh + 1152 + o);
            ga[i] = *(const h2*)(gatth + o);
        }
    for (int si = 0; si < 4; si++){
        int s = sg*4 + si;
        float f0, f1;
        if (s == d){
            f0 = lea[(g*A_+s)*2]; f1 = lea[(g*A_+s)*2+1];
        } else {
            int el = s*11 + (d < s ? d : d-1);
            f0 = ldf(ea, (size_t)(g*E_+el)*2,   f);
            f1 = ldf(ea, (size_t)(g*E_+el)*2+1, f);
        }
        h2 f0h = (h2){(_Float16)f0, (_Float16)f0};
        h2 f1h = (h2){(_Float16)f1, (_Float16)f1};
        const _Float16* xls = xlr + (size_t)(g*A_+s)*2304;
        float* ap = alpha + ((size_t)(g*A_+d)*12 + s)*H_;
        #pragma unroll
        for (int hg = 0; hg < 3; hg++){
            float p = 0.f;
            #pragma unroll
            for (int j = 0; j < 3; j++){
                int o = hg*384 + co + 2*j;
                int i = hg*3 + j;
                h2 xl2 = *(const h2*)(xls + o);
                h2 m = xl2 + xr[i];
                m = g0[i]*f0h + m;
                m = g1[i]*f1h + m;
                unsigned mu = __builtin_bit_cast(unsigned, m) & 0x7fff7fffu;
                h2 am = __builtin_bit_cast(h2, mu);
                h2 q = m*c06 + am*c04;
                p = __builtin_amdgcn_fdot2(ga[i], q, p, false);
            }
            #pragma unroll
            for (int off=1; off<32; off<<=1) p += __shfl_xor(p, off);
            if ((lane & 31) == 0)
                ap[hg*2 + (lane>>5)] = p;
        }
    }
}

// ---- GAT segment softmax + aggregate; XCD-swizzled.
// Optionally: fused next-layer LN1 (xn_out != null) and/or final output store (out != null).
__global__ __launch_bounds__(192) void k_segagg(const _Float16* __restrict__ xlr,
                         const float* __restrict__ alpha,
                         const void* gbias, size_t gbOff, const int* flagp, float* xf,
                         void* out, const void* lng, const void* lnb, size_t lnOff, bf16* xn_out)
{
    __shared__ float al[12][6];
    __shared__ float w[12][6];
    __shared__ float sred[3], qred[3];
    const int f = *flagp;
    int bid = blockIdx.x;
    int xcd = bid & 7, slot = bid >> 3;
    int gl = xcd*80 + slot/12;
    int a = slot % 12;
    int node = gl*A_ + a;
    int tid = threadIdx.x;
    if (tid < 72) ((float*)al)[tid] = alpha[(size_t)node*72 + tid];
    __syncthreads();
    if (tid < 6){
        float m = -1e30f;
        #pragma unroll
        for (int s=0;s<12;s++) m = fmaxf(m, al[s][tid]);
        float den = 0.f;
        #pragma unroll
        for (int s=0;s<12;s++){ float ex = expf(al[s][tid]-m); w[s][tid] = ex; den += ex; }
        float inv = 1.f/den;
        #pragma unroll
        for (int s=0;s<12;s++) w[s][tid] *= inv;
    }
    __syncthreads();
    int c = tid;
    float acc = 0.f;
    for (int s=0;s<12;s++){
        const _Float16* xp = xlr + (size_t)(gl*A_ + s)*2304 + c;
        #pragma unroll
        for (int h=0;h<6;h++) acc += w[s][h]*(float)xp[h*192];
    }
    int b = gl / T_, t = gl % T_;
    int xrow = (b*A_ + a)*T_ + t;
    size_t idx = (size_t)xrow*192 + c;
    float newv = xf[idx] + acc*(1.f/6.f) + ldf(gbias, gbOff + c, f);
    xf[idx] = newv;
    if (out){
        if (f) ((bf16*)out)[1474560 + idx] = __float2bfloat16(newv);
        else   ((float*)out)[1474560 + idx] = newv;
    }
    if (xn_out){
        // fused next-layer LN1: block owns the full row (192 channels)
        float sv = newv, qv2 = newv*newv;
        #pragma unroll
        for (int off=32; off; off>>=1){ sv += __shfl_xor(sv, off); qv2 += __shfl_xor(qv2, off); }
        int wid = tid >> 6;
        if ((tid & 63) == 0){ sred[wid] = sv; qred[wid] = qv2; }
        __syncthreads();
        float S = sred[0] + sred[1] + sred[2];
        float Q = qred[0] + qred[1] + qred[2];
        float mean = S * (1.f/192.f);
        float var  = Q * (1.f/192.f) - mean*mean;
        float rs = rsqrtf(var + 1e-5f);
        xn_out[idx] = __float2bfloat16((newv-mean)*rs*ldf(lng, lnOff+c, f) + ldf(lnb, lnOff+c, f));
    }
}

extern "C" void kernel_launch(void* const* d_in, const int* in_sizes, int n_in,
                              void* d_out, int out_size, void* d_ws, size_t ws_size,
                              hipStream_t stream)
{
    const void* sf   = d_in[0];
    const int* ids  = (const int*)d_in[2];
    const int* eidx = (const int*)d_in[3];
    const void* ea   = d_in[4];
    const void* emb  = d_in[5];
    const void *laW1=d_in[6],  *lab1=d_in[7];
    const void *bn1g=d_in[8],  *bn1b=d_in[9],  *bn1m=d_in[10], *bn1v=d_in[11];
    const void *laW2=d_in[12], *lab2=d_in[13];
    const void *bn2g=d_in[14], *bn2b=d_in[15], *bn2m=d_in[16], *bn2v=d_in[17];
    const void *laW3=d_in[18], *lab3=d_in[19];
    const void *bn3g=d_in[20], *bn3b=d_in[21], *bn3m=d_in[22], *bn3v=d_in[23];
    const void *ln1g=d_in[24], *ln1b=d_in[25];
    const void *qkvw=d_in[26], *qkvb=d_in[27];
    const void *outw=d_in[28], *outb=d_in[29];
    const void *ln2g=d_in[30], *ln2b=d_in[31];
    const void *fw1 =d_in[32], *fb1 =d_in[33];
    const void *fw2 =d_in[34], *fb2 =d_in[35];
    const void *gwl =d_in[36], *gbl =d_in[37];
    const void *gwr =d_in[38], *gbr =d_in[39];
    const void *gwe =d_in[40];
    const void *gatt=d_in[41];
    const void *gbias=d_in[42];
    const void *ng  =d_in[43], *nb  =d_in[44];

    float* ws = (float*)d_ws;
    float* xf  = ws;                          // [0, 1474560)
    bf16*  xn  = (bf16*)(ws + 1474560);       // 1,474,560 bf16
    bf16*  qkv = (bf16*)(ws + 2211840);       // 4,423,680 bf16
    bf16*  ao  = (bf16*)(ws + 4423680);       // 1,474,560 bf16
    bf16*  hb  = (bf16*)(ws + 2211840);       // overlays qkv+ao (FFN hidden)
    bf16*  h2g = (bf16*)(ws + 2211840);       // overlays (MLP hidden)
    bf16*  xlr = (bf16*)(ws + 2211840);       // overlays (GAT full lr: 17,694,720 fp16)
    float* lea = ws + 11059200;               // 15,360
    int*  flag = (int*)(ws + 11074560);
    bf16*  WB  = (bf16*)(ws + 11074568);      // 2,731,136 x 2B
    float* BB  = ws + 12440136;               // 12,608 f32
    float* alp = ws + 12452744;               // 552,960 f32 (dense [node][src][head])
    (void)ws_size; (void)in_sizes; (void)n_in; (void)out_size;

    k_detect<<<1, 1, 0, stream>>>(sf, flag);
    k_convert<<<(WB_TOT+BB_TOT+255)/256, 256, 0, stream>>>(
        qkvw, outw, fw1, fw2, gwl, gwr, gwe, gatt,
        laW1, lab1, bn1g, bn1b, bn1m, bn1v,
        laW2, lab2, bn2g, bn2b, bn2m, bn2v,
        laW3, lab3, bn3g, bn3b, bn3m, bn3v,
        qkvb, outb, fb1, fb2, gbl, gbr, flag, WB, BB);
    k_mlp_a<<<ROWS_/16, 256, 0, stream>>>(sf, ids, emb, flag, WB, BB, h2g);
    k_mgemm<<<dim3(ROWS_/64, 3), 256, 0, stream>>>(h2g, WB + WB_W3T, BB + BB_B3,
        nullptr, xf, nullptr, d_out, flag, 256, 192, 3);
    k_loopea<<<G_, 192, 0, stream>>>(eidx, ea, flag, lea);

    for (int l=0; l<3; l++){
        if (l == 0)
            k_ln<<<ROWS_/4, 256, 0, stream>>>(xf, ln1g, ln1b, 0, flag, xn, 0);
        // else: xn already produced by previous layer's fused segagg
        k_mgemm128<<<dim3(ROWS_/128, 9), 256, 0, stream>>>(xn, WB + WB_QKV + (size_t)l*110592,
            BB + BB_QKV + l*576, qkv, 192, 576, 0);
        k_attn<<<N_*H_, 320, 0, stream>>>(qkv, ao);
        k_mgemm<<<dim3(ROWS_/64, 3), 256, 0, stream>>>(ao, WB + WB_OUT + (size_t)l*36864,
            BB + BB_OUT + l*192, nullptr, xf, xf, nullptr, nullptr, 192, 192, 2);
        k_ln<<<ROWS_/4, 256, 0, stream>>>(xf, ln2g, ln2b, (size_t)l*192, flag, xn, 0);
        k_mgemm128<<<dim3(ROWS_/128, 12), 256, 0, stream>>>(xn, WB + WB_FW1 + (size_t)l*147456,
            BB + BB_FW1 + l*768, hb, 192, 768, 1);
        k_mgemm<<<dim3(ROWS_/64, 3), 256, 0, stream>>>(hb, WB + WB_FW2 + (size_t)l*147456,
            BB + BB_FW2 + l*192, nullptr, xf, xf, nullptr, nullptr, 768, 192, 2);
        k_ln<<<ROWS_/4, 256, 0, stream>>>(xf, ng, nb, (size_t)l*192, flag, xn, 1);
        k_mgemm128<<<dim3(ROWS_/128, 36), 256, 0, stream>>>(xn, WB + WB_GAT + (size_t)l*442368,
            BB + BB_GAT + l*2304, xlr, 192, 2304, 4);
        k_alpha<<<G_*36/4, 256, 0, stream>>>((const _Float16*)xlr, lea, ea,
            (const _Float16*)(WB + WB_GWE) + (size_t)l*2304,
            (const _Float16*)(WB + WB_GATT) + (size_t)l*1152, flag, alp);
        k_segagg<<<G_*A_, 192, 0, stream>>>((const _Float16*)xlr, alp, gbias, (size_t)l*192, flag, xf,
            l == 2 ? d_out : nullptr,
            l < 2 ? ln1g : nullptr, ln1b, (size_t)(l+1)*192,
            l < 2 ? xn : nullptr);
    }
}